// Round 8
// baseline (124.737 us; speedup 1.0000x reference)
//
#include <hip/hip_runtime.h>
#include <hip/hip_bf16.h>
#include <math.h>

// Problem constants
#define L_SEQ   1024
#define NB      8
#define H_DIM   300
#define KWIN    5
#define NREL    11          // 2K+1
#define PDIM    50
#define NC      11234       // band pair count for L=1024, K=5
#define BNC     (NB*NC)     // 89872
#define LN_EPS  1e-5f

#define KPAD    320         // K padded with zeros in [300,320)
#define WKSTR   320         // Wb k-stride (shorts)
#define WNPAD   320         // Wb padded n rows

#define ITILE   32          // i rows per block
#define NTB     32          // i-tiles per batch
#define THREADS 1024        // 16 waves
#define HROWS   42          // hc halo rows: i0-5 .. i0+36
#define XROWS   96          // 0..31 he/Ae (E0,E1), 32..79 hc/Ac (C0,C1,C2;
                            // 74..79 zero), 80..90 Pb, 91 ones, 92..95 zero
#define XSTR    328         // X row stride in shorts
#define NPAIR   (ITILE*NREL)  // 352

// Workspace layout (float offsets)
#define WB_OFF   2048       // prelbf (11*328 shorts = 7216 B) lives at 0
                            // Wb: 2*320*320 shorts = 102400 floats

typedef __attribute__((ext_vector_type(8))) short s16x8;
typedef __attribute__((ext_vector_type(4))) short s16x4;
typedef __attribute__((ext_vector_type(4))) float f32x4;

__device__ __forceinline__ short f2bf(float f) {
    unsigned u = __float_as_uint(f);
    u += 0x7fffu + ((u >> 16) & 1u);
    return (short)(u >> 16);
}
__device__ __forceinline__ float bf2f(short s) {
    return __uint_as_float(((unsigned)(unsigned short)s) << 16);
}

// band row start: first linear index n of row i
__device__ __forceinline__ int rowstart(int i) {
    if (i < 5)     return 6 * i + (i * (i - 1)) / 2;
    if (i <= 1018) return 40 + (i - 5) * 11;
    int d = i - 1019;
    return 11194 + d * 10 - (d * (d - 1)) / 2;
}

// ---------------------------------------------------------------------------
// Kernel 1: prep (unchanged).
__global__ __launch_bounds__(256) void prep_kernel(
    const float* __restrict__ pos_W, const float* __restrict__ W1,
    const float* __restrict__ b1, short* __restrict__ prelbf,
    short* __restrict__ Wb)
{
    if (blockIdx.x < 15) {
        __shared__ float semb[NREL * PDIM];
        for (int t = threadIdx.x; t < NREL * PDIM; t += 256) {
            int r = t / PDIM, d = t % PDIM;
            float acc = 0.f;
#pragma unroll
            for (int r2 = 0; r2 < NREL; ++r2) {
                float cnt = (float)(L_SEQ - abs(r2 - KWIN));
                int dr = r - r2;
                acc += cnt * expf(-(float)(dr * dr)) * pos_W[r2 * PDIM + d];
            }
            semb[t] = acc;
        }
        __syncthreads();
        int t = blockIdx.x * 256 + threadIdx.x;
        if (t < NREL * XSTR) {
            int r = t / XSTR, h = t % XSTR;
            float acc = 0.f;
            if (h < H_DIM) {
                acc = b1[h];
                const float* wrow = W1 + (size_t)h * 650 + 600;
                const float* em = semb + r * PDIM;
#pragma unroll 10
                for (int d = 0; d < PDIM; ++d) acc += wrow[d] * em[d];
            }
            prelbf[t] = (h < H_DIM) ? f2bf(acc) : (short)0;
        }
    } else {
        // 2*320*320 shorts = 25600 s16x8 chunks over 100 blocks
        int c = (blockIdx.x - 15) * 256 + threadIdx.x;
        if (c < 25600) {
            int z   = c / 12800;
            int rem = c - z * 12800;
            int n   = rem / 40;
            int k0  = (rem - n * 40) * 8;
            s16x8 v8 = (s16x8){0,0,0,0,0,0,0,0};
            if (n < H_DIM) {
                const float* base = W1 + (size_t)n * 650 + z * H_DIM;
#pragma unroll
                for (int e = 0; e < 8; ++e) {
                    int k = k0 + e;
                    float v = 0.f;
                    if (k < H_DIM) v = base[k];
                    v8[e] = f2bf(v);
                }
            }
            *(s16x8*)&Wb[(size_t)c * 8] = v8;
        }
    }
}

// ---------------------------------------------------------------------------
// Kernel 2: fused GEMM + Gram + epilogue. Block = (b, i-tile of 32),
// 1024 threads (16 waves), grid 256. Same phase structure/mapping as r7;
// adds: (1) Wb prologue-prefetch (k=0 loads issued before staging, complete
// for free) + 2-deep k-pipeline (k+1 B-frags loaded before k's MFMAs);
// (2) batched staging (3 tasks/thread, all loads issued before converts).
// Registers ~80-100 unified — under the 128 wave-cliff (m69).
// NO min-waves launch_bounds (r1-r3: caps -> catastrophic spills).
__global__ __launch_bounds__(THREADS) void fused_kernel(
    const float* __restrict__ h_e, const float* __restrict__ h_c,
    const float* __restrict__ h_share, const short* __restrict__ Wb,
    const short* __restrict__ prelbf,
    const float* __restrict__ ln_g, const float* __restrict__ ln_b,
    const float* __restrict__ W2, const float* __restrict__ b2,
    float* __restrict__ out, float* __restrict__ posout)
{
    __shared__ __align__(16) short X[XROWS * XSTR];   // 62976 B
    __shared__ __align__(16) float GL[9 * 272];       // 9792 B (9 full frags)
    __shared__ __align__(16) float SSeA[32];
    __shared__ __align__(16) float SScA[48];
    __shared__ __align__(16) float SSpA[16];
    __shared__ __align__(16) float SpA[16];
    __shared__ __align__(16) float SG[320];
    __shared__ __align__(16) float SB[320];
    __shared__ __align__(16) float SW[320];

    const int tid = threadIdx.x;
    const int b   = blockIdx.x >> 5;          // 32 i-tiles per batch
    const int i0  = (blockIdx.x & 31) * ITILE;

    const int wave = tid >> 6, lane = tid & 63;
    const int fr = lane & 15, fq = lane >> 4;
    const bool isPP = (wave == 12);
    const bool isE  = (wave < 5);
    const int  cw   = (isE || isPP) ? 0 : ((wave < 12) ? (wave - 5) : (wave - 6));
    const short* wbase = isE
        ? Wb + ((size_t)(wave * 64 + fr)) * WKSTR + fq * 8
        : Wb + ((size_t)(WNPAD + cw * 32 + fr)) * WKSTR + fq * 8;

    // ---- Wb prologue prefetch (k=0): completes during staging for free.
    s16x8 pb0, pb1, pb2, pb3;
    if (isE) {
        pb0 = *(const s16x8*)(wbase);
        pb1 = *(const s16x8*)(wbase + 16 * WKSTR);
        pb2 = *(const s16x8*)(wbase + 32 * WKSTR);
        pb3 = *(const s16x8*)(wbase + 48 * WKSTR);
    } else if (!isPP) {
        pb0 = *(const s16x8*)(wbase);
        pb1 = *(const s16x8*)(wbase + 16 * WKSTR);
    }

    // ---- zero-fill: rows 74..79 & 92..95 full width (10*41) + rows 0..73
    // cols [304,328) (74*3) = 632 16B chunks
    for (int t = tid; t < 632; t += THREADS) {
        int row, c;
        if (t < 410) { int rr2 = t / 41; row = rr2 < 6 ? 74 + rr2 : 92 + (rr2 - 6); c = (t % 41) * 8; }
        else         { int u = t - 410; row = u / 3; c = 304 + (u % 3) * 8; }
        *(s16x8*)&X[row * XSTR + c] = (s16x8){0,0,0,0,0,0,0,0};
    }
    // ---- ones row (91): bf16(1.0)=0x3F80 for cols<300, else 0
    for (int t = tid; t < XSTR; t += THREADS)
        X[91 * XSTR + t] = (t < H_DIM) ? (short)0x3F80 : (short)0;
    // ---- Pb rows 80..90: straight copy from prelbf (layout matches)
    for (int t = tid; t < NREL * 41; t += THREADS) {
        int r = t / 41, c = (t % 41) * 8;
        *(s16x8*)&X[(80 + r) * XSTR + c] = *(const s16x8*)(prelbf + r * XSTR + c);
    }
    // ---- LN params to LDS (zero pad to 320)
    if (tid < 320) {
        bool v = tid < H_DIM;
        SG[tid] = v ? ln_g[tid] : 0.f;
        SB[tid] = v ? ln_b[tid] : 0.f;
        SW[tid] = v ? W2[tid]   : 0.f;
    }
    // ---- stage 42 halo rows, batched: 3 tasks/thread (all loads issued
    // before converts) + 120-thread tail. h_share read once per row.
    {
        float4 hsv[3], hcv[3], hev[3];
        int    sA[3], kcA[3];
        bool   eA[3];
#pragma unroll
        for (int it = 0; it < 3; ++it) {
            const int t = tid + it * 1024;      // < 3072 < 3192
            const int s = t / 76, kc = (t % 76) * 4;
            const int g = i0 - KWIN + s;
            const bool valid = (kc < H_DIM) && (g >= 0) && (g < L_SEQ);
            const bool hasE  = (s >= KWIN) && (s < KWIN + ITILE);
            sA[it] = s; kcA[it] = kc; eA[it] = hasE;
            float4 z = make_float4(0.f, 0.f, 0.f, 0.f);
            hsv[it] = z; hcv[it] = z; hev[it] = z;
            if (valid) {
                const size_t off = ((size_t)b * L_SEQ + g) * H_DIM + kc;
                hsv[it] = *(const float4*)(h_share + off);
                hcv[it] = *(const float4*)(h_c + off);
                if (hasE) hev[it] = *(const float4*)(h_e + off);
            }
        }
#pragma unroll
        for (int it = 0; it < 3; ++it) {
            const int s = sA[it], kc = kcA[it];
            s16x4 vc = { f2bf(hcv[it].x + hsv[it].x), f2bf(hcv[it].y + hsv[it].y),
                         f2bf(hcv[it].z + hsv[it].z), f2bf(hcv[it].w + hsv[it].w) };
            *(s16x4*)&X[(32 + s) * XSTR + kc] = vc;
            if (eA[it]) {
                s16x4 ve = { f2bf(hev[it].x + hsv[it].x), f2bf(hev[it].y + hsv[it].y),
                             f2bf(hev[it].z + hsv[it].z), f2bf(hev[it].w + hsv[it].w) };
                *(s16x4*)&X[(s - KWIN) * XSTR + kc] = ve;
            }
        }
        if (tid < HROWS * 76 - 3072) {          // 120 tail tasks
            const int t = tid + 3072;
            const int s = t / 76, kc = (t % 76) * 4;
            const int g = i0 - KWIN + s;
            const bool valid = (kc < H_DIM) && (g >= 0) && (g < L_SEQ);
            float4 hs4 = make_float4(0.f,0.f,0.f,0.f), hc4 = hs4;
            if (valid) {
                const size_t off = ((size_t)b * L_SEQ + g) * H_DIM + kc;
                hs4 = *(const float4*)(h_share + off);
                hc4 = *(const float4*)(h_c + off);
            }
            s16x4 vc = { f2bf(hc4.x + hs4.x), f2bf(hc4.y + hs4.y),
                         f2bf(hc4.z + hs4.z), f2bf(hc4.w + hs4.w) };
            *(s16x4*)&X[(32 + s) * XSTR + kc] = vc;
            if (s >= KWIN && s < KWIN + ITILE) {
                float4 he4 = make_float4(0.f,0.f,0.f,0.f);
                if (valid) {
                    const size_t off = ((size_t)b * L_SEQ + g) * H_DIM + kc;
                    he4 = *(const float4*)(h_e + off);
                }
                s16x4 ve = { f2bf(he4.x + hs4.x), f2bf(he4.y + hs4.y),
                             f2bf(he4.z + hs4.z), f2bf(he4.w + hs4.w) };
                *(s16x4*)&X[(s - KWIN) * XSTR + kc] = ve;
            }
        }
    }
    __syncthreads();

    // ---- Main GEMM (15 waves, 2-deep Wb pipeline) + PP Gram (wave 12).
    f32x4 acc[8] = {};

    if (isPP) {
        // P.P Gram (rows 80..95): only depends on staged Pb/ones rows.
        f32x4 gp = {};
        for (int k0 = 0; k0 < KPAD; k0 += 32) {
            s16x8 av = *(const s16x8*)&X[(80 + fr) * XSTR + k0 + fq * 8];
            gp = __builtin_amdgcn_mfma_f32_16x16x32_bf16(av, av, gp, 0, 0, 0);
        }
#pragma unroll
        for (int r2 = 0; r2 < 4; ++r2) {
            if (fr == fq * 4 + r2) SSpA[fr] = gp[r2];
            if (fr == 11)          SpA[fq * 4 + r2] = gp[r2];
        }
    } else if (isE) {
        // E-half: wave e owns Wb cols [e*64, e*64+64), M tiles E0,E1.
        s16x8 b0 = pb0, b1 = pb1, b2 = pb2, b3 = pb3;
#pragma unroll
        for (int ks = 0; ks < 10; ++ks) {
            const int k0 = ks * 32;
            const int kn = (ks < 9) ? k0 + 32 : k0;   // last: dummy reload
            s16x8 n0 = *(const s16x8*)(wbase + kn);
            s16x8 n1 = *(const s16x8*)(wbase + 16 * WKSTR + kn);
            s16x8 n2 = *(const s16x8*)(wbase + 32 * WKSTR + kn);
            s16x8 n3 = *(const s16x8*)(wbase + 48 * WKSTR + kn);
            s16x8 a0 = *(const s16x8*)&X[fr * XSTR + k0 + fq * 8];
            s16x8 a1 = *(const s16x8*)&X[(16 + fr) * XSTR + k0 + fq * 8];
            __builtin_amdgcn_s_setprio(1);
            acc[0] = __builtin_amdgcn_mfma_f32_16x16x32_bf16(a0, b0, acc[0], 0, 0, 0);
            acc[4] = __builtin_amdgcn_mfma_f32_16x16x32_bf16(a1, b0, acc[4], 0, 0, 0);
            acc[1] = __builtin_amdgcn_mfma_f32_16x16x32_bf16(a0, b1, acc[1], 0, 0, 0);
            acc[5] = __builtin_amdgcn_mfma_f32_16x16x32_bf16(a1, b1, acc[5], 0, 0, 0);
            acc[2] = __builtin_amdgcn_mfma_f32_16x16x32_bf16(a0, b2, acc[2], 0, 0, 0);
            acc[6] = __builtin_amdgcn_mfma_f32_16x16x32_bf16(a1, b2, acc[6], 0, 0, 0);
            acc[3] = __builtin_amdgcn_mfma_f32_16x16x32_bf16(a0, b3, acc[3], 0, 0, 0);
            acc[7] = __builtin_amdgcn_mfma_f32_16x16x32_bf16(a1, b3, acc[7], 0, 0, 0);
            __builtin_amdgcn_s_setprio(0);
            b0 = n0; b1 = n1; b2 = n2; b3 = n3;
        }
    } else {
        // C-half: cw owns Wb cols [cw*32, cw*32+32), M tiles C0,C1,C2.
        s16x8 b0 = pb0, b1 = pb1;
#pragma unroll
        for (int ks = 0; ks < 10; ++ks) {
            const int k0 = ks * 32;
            const int kn = (ks < 9) ? k0 + 32 : k0;   // last: dummy reload
            s16x8 n0 = *(const s16x8*)(wbase + kn);
            s16x8 n1 = *(const s16x8*)(wbase + 16 * WKSTR + kn);
            s16x8 a0 = *(const s16x8*)&X[(32 + fr) * XSTR + k0 + fq * 8];
            s16x8 a1 = *(const s16x8*)&X[(48 + fr) * XSTR + k0 + fq * 8];
            s16x8 a2 = *(const s16x8*)&X[(64 + fr) * XSTR + k0 + fq * 8];
            __builtin_amdgcn_s_setprio(1);
            acc[0] = __builtin_amdgcn_mfma_f32_16x16x32_bf16(a0, b0, acc[0], 0, 0, 0);
            acc[2] = __builtin_amdgcn_mfma_f32_16x16x32_bf16(a1, b0, acc[2], 0, 0, 0);
            acc[4] = __builtin_amdgcn_mfma_f32_16x16x32_bf16(a2, b0, acc[4], 0, 0, 0);
            acc[1] = __builtin_amdgcn_mfma_f32_16x16x32_bf16(a0, b1, acc[1], 0, 0, 0);
            acc[3] = __builtin_amdgcn_mfma_f32_16x16x32_bf16(a1, b1, acc[3], 0, 0, 0);
            acc[5] = __builtin_amdgcn_mfma_f32_16x16x32_bf16(a2, b1, acc[5], 0, 0, 0);
            __builtin_amdgcn_s_setprio(0);
            b0 = n0; b1 = n1;
        }
    }
    __syncthreads();   // all waves done reading X he/hc inputs

    // ---- write Ae/Ac into X (bf16). C/D: col within slice +nt*16+fr,
    // row = tile_base + fq*4 + r2. Cols >= 300 compute to 0 (Wb zero cols).
    if (!isPP) {
        if (isE) {
            const int c0 = wave * 64;
#pragma unroll
            for (int nt = 0; nt < 4; ++nt) {
                const int col = c0 + nt * 16 + fr;
#pragma unroll
                for (int r2 = 0; r2 < 4; ++r2) {
                    X[(fq * 4 + r2) * XSTR + col]      = f2bf(acc[nt][r2]);
                    X[(16 + fq * 4 + r2) * XSTR + col] = f2bf(acc[4 + nt][r2]);
                }
            }
        } else {
            const int c0 = cw * 32;
#pragma unroll
            for (int nt = 0; nt < 2; ++nt) {
                const int col = c0 + nt * 16 + fr;
#pragma unroll
                for (int m = 0; m < 3; ++m)
#pragma unroll
                    for (int r2 = 0; r2 < 4; ++r2)
                        X[(32 + m * 16 + fq * 4 + r2) * XSTR + col] = f2bf(acc[2 * m + nt][r2]);
            }
        }
    }
    __syncthreads();

    // ---- Gram: the 15 needed fragments over 96 rows (k=320).
    // Tiles: E0=0,E1=16,C0=32,C1=48,C2=64,P=80.
    // waves 0..8 full frags: EC {(0,32),(0,48),(16,48),(16,64)},
    // EP {(0,80),(16,80)}, CP {(32,80),(48,80),(64,80)} -> GL[w].
    // diag (1 job/wave): 9:E0->SSeA, 10:E1->SSeA+16, 11:C0->SScA,
    // 13:C1->SScA+16, 14:C2->SScA+32. (PP by wave 12 earlier.)
    if (wave < 9) {
        int mrow, nrow;
        if (wave < 2)       { mrow = 0;                nrow = 32 + 16 * wave; }
        else if (wave == 2) { mrow = 16;               nrow = 48; }
        else if (wave == 3) { mrow = 16;               nrow = 64; }
        else if (wave < 6)  { mrow = 16 * (wave - 4);  nrow = 80; }
        else                { mrow = 32 + 16 * (wave - 6); nrow = 80; }
        f32x4 ga = {};
        for (int k0 = 0; k0 < KPAD; k0 += 32) {
            s16x8 av = *(const s16x8*)&X[(mrow + fr) * XSTR + k0 + fq * 8];
            s16x8 bv = *(const s16x8*)&X[(nrow + fr) * XSTR + k0 + fq * 8];
            ga = __builtin_amdgcn_mfma_f32_16x16x32_bf16(av, bv, ga, 0, 0, 0);
        }
#pragma unroll
        for (int r2 = 0; r2 < 4; ++r2)
            GL[wave * 272 + (fq * 4 + r2) * 17 + fr] = ga[r2];
    } else if (wave == 9 || wave == 10 || wave == 11 || wave == 13 || wave == 14) {
        int rbase;
        float* dst;
        if (wave == 9)       { rbase = 0;  dst = SSeA; }
        else if (wave == 10) { rbase = 16; dst = SSeA + 16; }
        else if (wave == 11) { rbase = 32; dst = SScA; }
        else if (wave == 13) { rbase = 48; dst = SScA + 16; }
        else                 { rbase = 64; dst = SScA + 32; }
        f32x4 ga = {};
        for (int k0 = 0; k0 < KPAD; k0 += 32) {
            s16x8 av = *(const s16x8*)&X[(rbase + fr) * XSTR + k0 + fq * 8];
            ga = __builtin_amdgcn_mfma_f32_16x16x32_bf16(av, av, ga, 0, 0, 0);
        }
#pragma unroll
        for (int r2 = 0; r2 < 4; ++r2)
            if (fr == fq * 4 + r2) dst[fr] = ga[r2];
    }
    __syncthreads();

    // ---- Epilogue: 1 pair per 16-lane quad, 64 quads, 6 rounds (352 pairs).
    const int quad = lane >> 4, fl = lane & 15;
    const int qq = wave * 4 + quad;            // 0..63
    const float b2v = b2[0];
    const float inv = 1.f / (float)H_DIM;

    for (int round = 0; round < 6; ++round) {
        const int q = round * 64 + qq;          // 0..383
        const int qc = q < NPAIR - 1 ? q : NPAIR - 1;
        const int di = qc / NREL, rr = qc % NREL;
        const int ii = i0 + di, j = ii - KWIN + rr;
        const bool active = (q < NPAIR) && (j >= 0) && (j < L_SEQ);

        const int Et = di >> 4, et = di & 15;
        const int hidx = di + rr;               // 0..41
        const int Ct = hidx >> 4, ct = hidx & 15;
        const int fEC = Et ? (1 + Ct) : Ct;     // (0,32)(0,48)(16,48)(16,64)

        const float Dec = GL[fEC * 272 + et * 17 + ct];
        const float Dep = GL[(4 + Et) * 272 + et * 17 + rr];
        const float Se  = GL[(4 + Et) * 272 + et * 17 + 11];
        const float Dcp = GL[(6 + Ct) * 272 + ct * 17 + rr];
        const float Sc  = GL[(6 + Ct) * 272 + ct * 17 + 11];
        const float SSe = SSeA[di];
        const float SSc = SScA[hidx];
        const float SSp = SSpA[rr];
        const float Sp  = SpA[rr];

        const float mu   = (Se + Sc + Sp) * inv;
        const float ss   = SSe + SSc + SSp + 2.f * (Dec + Dep + Dcp);
        const float rsig = rsqrtf(ss * inv - mu * mu + LN_EPS);
        const float nmrs = -mu * rsig;

        const int ea = di * XSTR;               // Ae row
        const int ca = (32 + hidx) * XSTR;      // Ac row
        const int pa = (80 + rr) * XSTR;        // Pb row

        float acc2e = 0.f;
#pragma unroll
        for (int w5 = 0; w5 < 5; ++w5) {
            const int c = w5 * 64 + fl * 4;     // 0..316, zero-padded
            s16x4 a0 = *(const s16x4*)&X[ea + c];
            s16x4 d0 = *(const s16x4*)&X[ca + c];
            s16x4 p0 = *(const s16x4*)&X[pa + c];
            float4 g  = *(const float4*)&SG[c];
            float4 bb = *(const float4*)&SB[c];
            float4 w  = *(const float4*)&SW[c];
#pragma unroll
            for (int e = 0; e < 4; ++e) {
                float v = bf2f(a0[e]) + bf2f(d0[e]) + bf2f(p0[e]);
                float t0 = fmaf(fmaf(v, rsig, nmrs), (&g.x)[e], (&bb.x)[e]);
                t0 = t0 > 0.f ? t0 : __expf(t0) - 1.f;
                acc2e = fmaf(t0, (&w.x)[e], acc2e);
            }
        }
#pragma unroll
        for (int off = 1; off < 16; off <<= 1) acc2e += __shfl_xor(acc2e, off);

        if (fl == 0 && active) {
            const int jb = ii - KWIN < 0 ? 0 : ii - KWIN;
            const int n = rowstart(ii) + (j - jb);
            out[(size_t)b * NC + n] = acc2e + b2v;
            if (b == 0) {
                posout[2 * (size_t)n]     = (float)(ii + 1);
                posout[2 * (size_t)n + 1] = (float)(j + 1);
            }
        }
    }
}

// ---------------------------------------------------------------------------
extern "C" void kernel_launch(void* const* d_in, const int* in_sizes, int n_in,
                              void* d_out, int out_size, void* d_ws, size_t ws_size,
                              hipStream_t stream) {
    const float* h_e     = (const float*)d_in[0];
    const float* h_c     = (const float*)d_in[1];
    const float* h_share = (const float*)d_in[2];
    // d_in[3] = mask (unused)
    const float* pos_W   = (const float*)d_in[4];
    const float* W1      = (const float*)d_in[5];
    const float* b1      = (const float*)d_in[6];
    const float* ln_g    = (const float*)d_in[7];
    const float* ln_b    = (const float*)d_in[8];
    const float* W2      = (const float*)d_in[9];
    const float* b2      = (const float*)d_in[10];

    float* ws     = (float*)d_ws;
    short* prelbf = (short*)ws;
    short* Wb     = (short*)(ws + WB_OFF);

    float* out    = (float*)d_out;
    float* posout = out + BNC;

    prep_kernel<<<115, 256, 0, stream>>>(pos_W, W1, b1, prelbf, Wb);

    fused_kernel<<<NB * NTB, THREADS, 0, stream>>>(
        h_e, h_c, h_share, Wb, prelbf, ln_g, ln_b, W2, b2, out, posout);
}

// Round 9
// 123.045 us; speedup vs baseline: 1.0138x; 1.0138x over previous
//
#include <hip/hip_runtime.h>
#include <hip/hip_bf16.h>
#include <math.h>

// Problem constants
#define L_SEQ   1024
#define NB      8
#define H_DIM   300
#define KWIN    5
#define NREL    11          // 2K+1
#define PDIM    50
#define NC      11234       // band pair count for L=1024, K=5
#define BNC     (NB*NC)     // 89872
#define LN_EPS  1e-5f

#define KPAD    320         // K padded with zeros in [300,320)
#define WKSTR   320         // Wb k-stride (shorts)
#define WNPAD   320         // Wb padded n rows

#define ITILE   32          // i rows per block
#define NTB     32          // i-tiles per batch
#define THREADS 1024        // 16 waves
#define HROWS   42          // hc halo rows: i0-5 .. i0+36
#define XROWS   91          // 0..31 he (E0,E1), 32..73 hc (C halo; 74..79 z),
                            // 80..90 Pb
#define ABROWS  80          // Ae rows 0..31, Ac rows 32..79
#define XSTR    328         // row stride in shorts
#define NPAIR   (ITILE*NREL)  // 352

// Workspace layout (float offsets)
#define WB_OFF   2048       // prelbf (11*328 shorts = 7216 B) lives at 0
                            // Wb: 2*320*320 shorts = 102400 floats

typedef __attribute__((ext_vector_type(8))) short s16x8;
typedef __attribute__((ext_vector_type(4))) short s16x4;
typedef __attribute__((ext_vector_type(4))) float f32x4;

__device__ __forceinline__ short f2bf(float f) {
    unsigned u = __float_as_uint(f);
    u += 0x7fffu + ((u >> 16) & 1u);
    return (short)(u >> 16);
}
__device__ __forceinline__ float bf2f(short s) {
    return __uint_as_float(((unsigned)(unsigned short)s) << 16);
}

// band row start: first linear index n of row i
__device__ __forceinline__ int rowstart(int i) {
    if (i < 5)     return 6 * i + (i * (i - 1)) / 2;
    if (i <= 1018) return 40 + (i - 5) * 11;
    int d = i - 1019;
    return 11194 + d * 10 - (d * (d - 1)) / 2;
}

// ---------------------------------------------------------------------------
// Kernel 1: prep (unchanged).
__global__ __launch_bounds__(256) void prep_kernel(
    const float* __restrict__ pos_W, const float* __restrict__ W1,
    const float* __restrict__ b1, short* __restrict__ prelbf,
    short* __restrict__ Wb)
{
    if (blockIdx.x < 15) {
        __shared__ float semb[NREL * PDIM];
        for (int t = threadIdx.x; t < NREL * PDIM; t += 256) {
            int r = t / PDIM, d = t % PDIM;
            float acc = 0.f;
#pragma unroll
            for (int r2 = 0; r2 < NREL; ++r2) {
                float cnt = (float)(L_SEQ - abs(r2 - KWIN));
                int dr = r - r2;
                acc += cnt * expf(-(float)(dr * dr)) * pos_W[r2 * PDIM + d];
            }
            semb[t] = acc;
        }
        __syncthreads();
        int t = blockIdx.x * 256 + threadIdx.x;
        if (t < NREL * XSTR) {
            int r = t / XSTR, h = t % XSTR;
            float acc = 0.f;
            if (h < H_DIM) {
                acc = b1[h];
                const float* wrow = W1 + (size_t)h * 650 + 600;
                const float* em = semb + r * PDIM;
#pragma unroll 10
                for (int d = 0; d < PDIM; ++d) acc += wrow[d] * em[d];
            }
            prelbf[t] = (h < H_DIM) ? f2bf(acc) : (short)0;
        }
    } else {
        // 2*320*320 shorts = 25600 s16x8 chunks over 100 blocks
        int c = (blockIdx.x - 15) * 256 + threadIdx.x;
        if (c < 25600) {
            int z   = c / 12800;
            int rem = c - z * 12800;
            int n   = rem / 40;
            int k0  = (rem - n * 40) * 8;
            s16x8 v8 = (s16x8){0,0,0,0,0,0,0,0};
            if (n < H_DIM) {
                const float* base = W1 + (size_t)n * 650 + z * H_DIM;
#pragma unroll
                for (int e = 0; e < 8; ++e) {
                    int k = k0 + e;
                    float v = 0.f;
                    if (k < H_DIM) v = base[k];
                    v8[e] = f2bf(v);
                }
            }
            *(s16x8*)&Wb[(size_t)c * 8] = v8;
        }
    }
}

// ---------------------------------------------------------------------------
// Kernel 2: fused GEMM + epilogue (Gram phases DELETED — LN stats computed
// in-epilogue from v kept in 20 regs; 2 barriers instead of 4).
// Block = (b, i-tile of 32), 1024 threads (16 waves), grid 256.
// All 16 waves GEMM, each Wb byte read once: E waves 0-3 (64 cols, 8 chains),
// 4-5 (32 cols, 4 chains); C waves 6-15 (32 cols, 6 chains).
// Ae/Ac written to separate ABUF (no WAR on X -> write fused into GEMM phase).
// 2-deep Wb pipeline + prologue prefetch + batched staging (r8).
// NO min-waves launch_bounds (r1-r3: caps -> catastrophic spills).
__global__ __launch_bounds__(THREADS) void fused_kernel(
    const float* __restrict__ h_e, const float* __restrict__ h_c,
    const float* __restrict__ h_share, const short* __restrict__ Wb,
    const short* __restrict__ prelbf,
    const float* __restrict__ ln_g, const float* __restrict__ ln_b,
    const float* __restrict__ W2, const float* __restrict__ b2,
    float* __restrict__ out, float* __restrict__ posout)
{
    __shared__ __align__(16) short X[XROWS * XSTR];    // 59696 B
    __shared__ __align__(16) short AB[ABROWS * XSTR];  // 52480 B
    __shared__ __align__(16) float SG[320];
    __shared__ __align__(16) float SB[320];
    __shared__ __align__(16) float SW[320];

    const int tid = threadIdx.x;
    const int b   = blockIdx.x >> 5;          // 32 i-tiles per batch
    const int i0  = (blockIdx.x & 31) * ITILE;

    const int wave = tid >> 6, lane = tid & 63;
    const int fr = lane & 15, fq = lane >> 4;
    const bool isE = (wave < 6);
    const int  c0  = (wave < 4) ? wave * 64
                   : (wave < 6) ? 256 + (wave - 4) * 32
                                : (wave - 6) * 32;
    const short* wbase = isE
        ? Wb + ((size_t)(c0 + fr)) * WKSTR + fq * 8
        : Wb + ((size_t)(WNPAD + c0 + fr)) * WKSTR + fq * 8;

    // ---- Wb prologue prefetch (k=0): completes during staging for free.
    s16x8 pb0, pb1, pb2, pb3;
    pb0 = *(const s16x8*)(wbase);
    pb1 = *(const s16x8*)(wbase + 16 * WKSTR);
    if (wave < 4) {
        pb2 = *(const s16x8*)(wbase + 32 * WKSTR);
        pb3 = *(const s16x8*)(wbase + 48 * WKSTR);
    }

    // ---- zero-fill: rows 74..79 full width (6*41=246) + rows 0..73 cols
    // [304,328) (74*3=222) = 468 16B chunks
    for (int t = tid; t < 468; t += THREADS) {
        int row, c;
        if (t < 246) { row = 74 + t / 41; c = (t % 41) * 8; }
        else         { int u = t - 246; row = u / 3; c = 304 + (u % 3) * 8; }
        *(s16x8*)&X[row * XSTR + c] = (s16x8){0,0,0,0,0,0,0,0};
    }
    // ---- Pb rows 80..90: straight copy from prelbf (layout matches,
    // zeros for cols >= 300 included)
    for (int t = tid; t < NREL * 41; t += THREADS) {
        int r = t / 41, c = (t % 41) * 8;
        *(s16x8*)&X[(80 + r) * XSTR + c] = *(const s16x8*)(prelbf + r * XSTR + c);
    }
    // ---- LN params to LDS (zero pad to 320)
    if (tid < 320) {
        bool v = tid < H_DIM;
        SG[tid] = v ? ln_g[tid] : 0.f;
        SB[tid] = v ? ln_b[tid] : 0.f;
        SW[tid] = v ? W2[tid]   : 0.f;
    }
    // ---- stage 42 halo rows, batched: 3 tasks/thread (all loads issued
    // before converts) + 120-thread tail. h_share read once per row.
    {
        float4 hsv[3], hcv[3], hev[3];
        int    sA[3], kcA[3];
        bool   eA[3];
#pragma unroll
        for (int it = 0; it < 3; ++it) {
            const int t = tid + it * 1024;      // < 3072 < 3192
            const int s = t / 76, kc = (t % 76) * 4;
            const int g = i0 - KWIN + s;
            const bool valid = (kc < H_DIM) && (g >= 0) && (g < L_SEQ);
            const bool hasE  = (s >= KWIN) && (s < KWIN + ITILE);
            sA[it] = s; kcA[it] = kc; eA[it] = hasE;
            float4 z = make_float4(0.f, 0.f, 0.f, 0.f);
            hsv[it] = z; hcv[it] = z; hev[it] = z;
            if (valid) {
                const size_t off = ((size_t)b * L_SEQ + g) * H_DIM + kc;
                hsv[it] = *(const float4*)(h_share + off);
                hcv[it] = *(const float4*)(h_c + off);
                if (hasE) hev[it] = *(const float4*)(h_e + off);
            }
        }
#pragma unroll
        for (int it = 0; it < 3; ++it) {
            const int s = sA[it], kc = kcA[it];
            s16x4 vc = { f2bf(hcv[it].x + hsv[it].x), f2bf(hcv[it].y + hsv[it].y),
                         f2bf(hcv[it].z + hsv[it].z), f2bf(hcv[it].w + hsv[it].w) };
            *(s16x4*)&X[(32 + s) * XSTR + kc] = vc;
            if (eA[it]) {
                s16x4 ve = { f2bf(hev[it].x + hsv[it].x), f2bf(hev[it].y + hsv[it].y),
                             f2bf(hev[it].z + hsv[it].z), f2bf(hev[it].w + hsv[it].w) };
                *(s16x4*)&X[(s - KWIN) * XSTR + kc] = ve;
            }
        }
        if (tid < HROWS * 76 - 3072) {          // 120 tail tasks
            const int t = tid + 3072;
            const int s = t / 76, kc = (t % 76) * 4;
            const int g = i0 - KWIN + s;
            const bool valid = (kc < H_DIM) && (g >= 0) && (g < L_SEQ);
            float4 hs4 = make_float4(0.f,0.f,0.f,0.f), hc4 = hs4;
            if (valid) {
                const size_t off = ((size_t)b * L_SEQ + g) * H_DIM + kc;
                hs4 = *(const float4*)(h_share + off);
                hc4 = *(const float4*)(h_c + off);
            }
            s16x4 vc = { f2bf(hc4.x + hs4.x), f2bf(hc4.y + hs4.y),
                         f2bf(hc4.z + hs4.z), f2bf(hc4.w + hs4.w) };
            *(s16x4*)&X[(32 + s) * XSTR + kc] = vc;
            if (s >= KWIN && s < KWIN + ITILE) {
                float4 he4 = make_float4(0.f,0.f,0.f,0.f);
                if (valid) {
                    const size_t off = ((size_t)b * L_SEQ + g) * H_DIM + kc;
                    he4 = *(const float4*)(h_e + off);
                }
                s16x4 ve = { f2bf(he4.x + hs4.x), f2bf(he4.y + hs4.y),
                             f2bf(he4.z + hs4.z), f2bf(he4.w + hs4.w) };
                *(s16x4*)&X[(s - KWIN) * XSTR + kc] = ve;
            }
        }
    }
    __syncthreads();

    // ---- GEMM (all 16 waves, 2-deep Wb pipeline) + fused ABUF write-back.
    {
        f32x4 acc[8] = {};
        if (wave < 4) {
            // E 64-col: 4 ntiles x 2 M-tiles (rows 0..15, 16..31) = 8 chains.
            s16x8 b0 = pb0, b1 = pb1, b2 = pb2, b3 = pb3;
#pragma unroll
            for (int ks = 0; ks < 10; ++ks) {
                const int k0 = ks * 32;
                const int kn = (ks < 9) ? k0 + 32 : k0;   // last: dummy reload
                s16x8 n0 = *(const s16x8*)(wbase + kn);
                s16x8 n1 = *(const s16x8*)(wbase + 16 * WKSTR + kn);
                s16x8 n2 = *(const s16x8*)(wbase + 32 * WKSTR + kn);
                s16x8 n3 = *(const s16x8*)(wbase + 48 * WKSTR + kn);
                s16x8 a0 = *(const s16x8*)&X[fr * XSTR + k0 + fq * 8];
                s16x8 a1 = *(const s16x8*)&X[(16 + fr) * XSTR + k0 + fq * 8];
                __builtin_amdgcn_s_setprio(1);
                acc[0] = __builtin_amdgcn_mfma_f32_16x16x32_bf16(a0, b0, acc[0], 0, 0, 0);
                acc[4] = __builtin_amdgcn_mfma_f32_16x16x32_bf16(a1, b0, acc[4], 0, 0, 0);
                acc[1] = __builtin_amdgcn_mfma_f32_16x16x32_bf16(a0, b1, acc[1], 0, 0, 0);
                acc[5] = __builtin_amdgcn_mfma_f32_16x16x32_bf16(a1, b1, acc[5], 0, 0, 0);
                acc[2] = __builtin_amdgcn_mfma_f32_16x16x32_bf16(a0, b2, acc[2], 0, 0, 0);
                acc[6] = __builtin_amdgcn_mfma_f32_16x16x32_bf16(a1, b2, acc[6], 0, 0, 0);
                acc[3] = __builtin_amdgcn_mfma_f32_16x16x32_bf16(a0, b3, acc[3], 0, 0, 0);
                acc[7] = __builtin_amdgcn_mfma_f32_16x16x32_bf16(a1, b3, acc[7], 0, 0, 0);
                __builtin_amdgcn_s_setprio(0);
                b0 = n0; b1 = n1; b2 = n2; b3 = n3;
            }
#pragma unroll
            for (int nt = 0; nt < 4; ++nt) {
                const int col = c0 + nt * 16 + fr;
#pragma unroll
                for (int r2 = 0; r2 < 4; ++r2) {
                    AB[(fq * 4 + r2) * XSTR + col]      = f2bf(acc[nt][r2]);
                    AB[(16 + fq * 4 + r2) * XSTR + col] = f2bf(acc[4 + nt][r2]);
                }
            }
        } else if (wave < 6) {
            // E 32-col: 2 ntiles x 2 M-tiles = 4 chains.
            s16x8 b0 = pb0, b1 = pb1;
#pragma unroll
            for (int ks = 0; ks < 10; ++ks) {
                const int k0 = ks * 32;
                const int kn = (ks < 9) ? k0 + 32 : k0;
                s16x8 n0 = *(const s16x8*)(wbase + kn);
                s16x8 n1 = *(const s16x8*)(wbase + 16 * WKSTR + kn);
                s16x8 a0 = *(const s16x8*)&X[fr * XSTR + k0 + fq * 8];
                s16x8 a1 = *(const s16x8*)&X[(16 + fr) * XSTR + k0 + fq * 8];
                __builtin_amdgcn_s_setprio(1);
                acc[0] = __builtin_amdgcn_mfma_f32_16x16x32_bf16(a0, b0, acc[0], 0, 0, 0);
                acc[2] = __builtin_amdgcn_mfma_f32_16x16x32_bf16(a1, b0, acc[2], 0, 0, 0);
                acc[1] = __builtin_amdgcn_mfma_f32_16x16x32_bf16(a0, b1, acc[1], 0, 0, 0);
                acc[3] = __builtin_amdgcn_mfma_f32_16x16x32_bf16(a1, b1, acc[3], 0, 0, 0);
                __builtin_amdgcn_s_setprio(0);
                b0 = n0; b1 = n1;
            }
#pragma unroll
            for (int nt = 0; nt < 2; ++nt) {
                const int col = c0 + nt * 16 + fr;
#pragma unroll
                for (int r2 = 0; r2 < 4; ++r2) {
                    AB[(fq * 4 + r2) * XSTR + col]      = f2bf(acc[nt][r2]);
                    AB[(16 + fq * 4 + r2) * XSTR + col] = f2bf(acc[2 + nt][r2]);
                }
            }
        } else {
            // C 32-col: 2 ntiles x 3 M-tiles (rows 32,48,64) = 6 chains.
            s16x8 b0 = pb0, b1 = pb1;
#pragma unroll
            for (int ks = 0; ks < 10; ++ks) {
                const int k0 = ks * 32;
                const int kn = (ks < 9) ? k0 + 32 : k0;
                s16x8 n0 = *(const s16x8*)(wbase + kn);
                s16x8 n1 = *(const s16x8*)(wbase + 16 * WKSTR + kn);
                s16x8 a0 = *(const s16x8*)&X[(32 + fr) * XSTR + k0 + fq * 8];
                s16x8 a1 = *(const s16x8*)&X[(48 + fr) * XSTR + k0 + fq * 8];
                s16x8 a2 = *(const s16x8*)&X[(64 + fr) * XSTR + k0 + fq * 8];
                __builtin_amdgcn_s_setprio(1);
                acc[0] = __builtin_amdgcn_mfma_f32_16x16x32_bf16(a0, b0, acc[0], 0, 0, 0);
                acc[2] = __builtin_amdgcn_mfma_f32_16x16x32_bf16(a1, b0, acc[2], 0, 0, 0);
                acc[4] = __builtin_amdgcn_mfma_f32_16x16x32_bf16(a2, b0, acc[4], 0, 0, 0);
                acc[1] = __builtin_amdgcn_mfma_f32_16x16x32_bf16(a0, b1, acc[1], 0, 0, 0);
                acc[3] = __builtin_amdgcn_mfma_f32_16x16x32_bf16(a1, b1, acc[3], 0, 0, 0);
                acc[5] = __builtin_amdgcn_mfma_f32_16x16x32_bf16(a2, b1, acc[5], 0, 0, 0);
                __builtin_amdgcn_s_setprio(0);
                b0 = n0; b1 = n1;
            }
#pragma unroll
            for (int nt = 0; nt < 2; ++nt) {
                const int col = c0 + nt * 16 + fr;
#pragma unroll
                for (int m = 0; m < 3; ++m)
#pragma unroll
                    for (int r2 = 0; r2 < 4; ++r2)
                        AB[(32 + m * 16 + fq * 4 + r2) * XSTR + col] = f2bf(acc[2 * m + nt][r2]);
            }
        }
    }
    __syncthreads();   // ABUF complete

    // ---- Epilogue: 1 pair per 16-lane quad, 64 quads, 6 rounds (352 pairs).
    // LN stats computed in-register: pass 1 loads v (kept in 20 regs),
    // accumulates s/ss, 8-shuffle butterfly; pass 2 normalizes from regs.
    const int quad = lane >> 4, fl = lane & 15;
    const int qq = wave * 4 + quad;            // 0..63
    const float b2v = b2[0];
    const float inv = 1.f / (float)H_DIM;

    for (int round = 0; round < 6; ++round) {
        const int q = round * 64 + qq;          // 0..383
        const int qc = q < NPAIR - 1 ? q : NPAIR - 1;
        const int di = qc / NREL, rr = qc % NREL;
        const int ii = i0 + di, j = ii - KWIN + rr;
        const bool active = (q < NPAIR) && (j >= 0) && (j < L_SEQ);

        const int hidx = di + rr;               // 0..41
        const int ea = di * XSTR;               // Ae row in AB (0..31)
        const int ca = (32 + hidx) * XSTR;      // Ac row in AB (32..73)
        const int pa = (80 + rr) * XSTR;        // Pb row in X

        float v[20];
        float s = 0.f, ss = 0.f;
#pragma unroll
        for (int w5 = 0; w5 < 5; ++w5) {
            const int c = w5 * 64 + fl * 4;     // 0..316, zero-padded >=300
            s16x4 a0 = *(const s16x4*)&AB[ea + c];
            s16x4 d0 = *(const s16x4*)&AB[ca + c];
            s16x4 p0 = *(const s16x4*)&X[pa + c];
#pragma unroll
            for (int e = 0; e < 4; ++e) {
                float vv = bf2f(a0[e]) + bf2f(d0[e]) + bf2f(p0[e]);
                v[w5 * 4 + e] = vv;
                s += vv;
                ss = fmaf(vv, vv, ss);
            }
        }
#pragma unroll
        for (int off = 1; off < 16; off <<= 1) {
            s  += __shfl_xor(s,  off);
            ss += __shfl_xor(ss, off);
        }
        const float mu   = s * inv;
        const float rsig = rsqrtf(ss * inv - mu * mu + LN_EPS);
        const float nmrs = -mu * rsig;

        float acc2 = 0.f;
#pragma unroll
        for (int w5 = 0; w5 < 5; ++w5) {
            const int c = w5 * 64 + fl * 4;
            float4 g  = *(const float4*)&SG[c];
            float4 bb = *(const float4*)&SB[c];
            float4 w  = *(const float4*)&SW[c];
#pragma unroll
            for (int e = 0; e < 4; ++e) {
                float t0 = fmaf(fmaf(v[w5 * 4 + e], rsig, nmrs), (&g.x)[e], (&bb.x)[e]);
                t0 = t0 > 0.f ? t0 : __expf(t0) - 1.f;
                acc2 = fmaf(t0, (&w.x)[e], acc2);
            }
        }
#pragma unroll
        for (int off = 1; off < 16; off <<= 1) acc2 += __shfl_xor(acc2, off);

        if (fl == 0 && active) {
            const int jb = ii - KWIN < 0 ? 0 : ii - KWIN;
            const int n = rowstart(ii) + (j - jb);
            out[(size_t)b * NC + n] = acc2 + b2v;
            if (b == 0) {
                posout[2 * (size_t)n]     = (float)(ii + 1);
                posout[2 * (size_t)n + 1] = (float)(j + 1);
            }
        }
    }
}

// ---------------------------------------------------------------------------
extern "C" void kernel_launch(void* const* d_in, const int* in_sizes, int n_in,
                              void* d_out, int out_size, void* d_ws, size_t ws_size,
                              hipStream_t stream) {
    const float* h_e     = (const float*)d_in[0];
    const float* h_c     = (const float*)d_in[1];
    const float* h_share = (const float*)d_in[2];
    // d_in[3] = mask (unused)
    const float* pos_W   = (const float*)d_in[4];
    const float* W1      = (const float*)d_in[5];
    const float* b1      = (const float*)d_in[6];
    const float* ln_g    = (const float*)d_in[7];
    const float* ln_b    = (const float*)d_in[8];
    const float* W2      = (const float*)d_in[9];
    const float* b2      = (const float*)d_in[10];

    float* ws     = (float*)d_ws;
    short* prelbf = (short*)ws;
    short* Wb     = (short*)(ws + WB_OFF);

    float* out    = (float*)d_out;
    float* posout = out + BNC;

    prep_kernel<<<115, 256, 0, stream>>>(pos_W, W1, b1, prelbf, Wb);

    fused_kernel<<<NB * NTB, THREADS, 0, stream>>>(
        h_e, h_c, h_share, Wb, prelbf, ln_g, ln_b, W2, b2, out, posout);
}